// Round 11
// baseline (190.381 us; speedup 1.0000x reference)
//
#include <hip/hip_runtime.h>

// AlgebraicAttention on MI355X (gfx950), round 11.
// R10 post-mortem: gemm_qkv FETCH 54MB vs 14MB unique inputs -> same-B-tile blocks at
// consecutive indices round-robin across XCDs, duplicating every B-tile into all 8 L2s.
// Fixes: (1) XCD remap: same-B blocks at stride-16/32 indices (≡ same mod 8) so each
// B-tile lives in one XCD's L2; (2) gemm_out linearized with same property;
// (3) attention K/V staged via source-swizzled global_load_lds (XOR is an involution:
// landing layout identical to r10's register path, minus the VGPR round-trip).
// ws: [0,8M) xb | [8,10M) wqb | [10,12M) wkb | [12,14M) wvb | [14,16M) wob |
//     [16,24M) Qb (att in-place). d_out: [0,8M) Kb | [8,16M) Vtg (V^T).

typedef __attribute__((ext_vector_type(8))) __bf16 bf16x8;
typedef __attribute__((ext_vector_type(4))) __bf16 bf16x4;
typedef __attribute__((ext_vector_type(4))) float f32x4;
typedef unsigned short u16;

__device__ __forceinline__ u16 f2bf(float f) {
  unsigned u = __float_as_uint(f);
  u += 0x7FFFu + ((u >> 16) & 1u);   // round-to-nearest-even
  return (u16)(u >> 16);
}
__device__ __forceinline__ float bf2f(u16 b) {
  return __uint_as_float(((unsigned)b) << 16);
}
__device__ __forceinline__ void gl_lds16(const void* g, void* l) {
  __builtin_amdgcn_global_load_lds((__attribute__((address_space(1))) void*)g,
                                   (__attribute__((address_space(3))) void*)l,
                                   16, 0, 0);
}

// ---------------------------------------------------------------- cast kernel
__global__ __launch_bounds__(256) void cast_all_kernel(
    const float* __restrict__ x,  const float* __restrict__ wq,
    const float* __restrict__ wk, const float* __restrict__ wv,
    const float* __restrict__ wo,
    u16* __restrict__ xb, u16* __restrict__ wqb, u16* __restrict__ wkb,
    u16* __restrict__ wvb, u16* __restrict__ wob) {
  long i4 = (long)blockIdx.x * 256 + threadIdx.x;
  const float* src; u16* dst; long rel;
  if (i4 < 1048576) { src = x; dst = xb; rel = i4; }
  else {
    long j = i4 - 1048576;
    int w = (int)(j >> 18);
    rel = j & 262143;
    src = (w == 0) ? wq : (w == 1) ? wk : (w == 2) ? wv : wo;
    dst = (w == 0) ? wqb : (w == 1) ? wkb : (w == 2) ? wvb : wob;
  }
  float4 v = ((const float4*)src)[rel];
  ushort4 o;
  o.x = f2bf(v.x); o.y = f2bf(v.y); o.z = f2bf(v.z); o.w = f2bf(v.w);
  ((ushort4*)dst)[rel] = o;
}

// ---------------------------------------------------------------- GEMM body (r9, proven)
// C = A @ B^T (+bias). 128x128 tile, BK=64, double-buffered swizzled LDS,
// raw s_barrier + vmcnt(8) pipeline. Conflicts measured 0.
template <bool STORE_BF16>
__device__ __forceinline__ void gemm_body(
    const u16* __restrict__ A, const u16* __restrict__ B,
    const float* __restrict__ bias, bool rowbias,
    void* __restrict__ Cout, int ldc, int m0, int n0) {
  constexpr int K = 1024;
  constexpr int NT = K / 64;
  __shared__ __align__(16) u16 As[2][128 * 64];
  __shared__ __align__(16) u16 Bs[2][128 * 64];

  const int t = threadIdx.x;
  const int lane = t & 63;
  const int wv = t >> 6;
  const int quad = lane >> 4;
  const int l15 = lane & 15;
  const int wr = wv >> 1, wc = wv & 1;
  const int sw0 = (quad ^ (l15 & 7)) * 8;
  const int sw1 = ((4 + quad) ^ (l15 & 7)) * 8;

  const f32x4 vzero = {0.f, 0.f, 0.f, 0.f};
  f32x4 acc[4][4];
#pragma unroll
  for (int i = 0; i < 4; ++i)
#pragma unroll
    for (int j = 0; j < 4; ++j) acc[i][j] = vzero;

  auto stage = [&](int kt, int bufi) {
#pragma unroll
    for (int p = 0; p < 4; ++p) {
      int idx = t + p * 256;
      int row = idx >> 3, seg = idx & 7;
      int sseg = seg ^ (row & 7);
      gl_lds16(&A[(long)(m0 + row) * K + kt * 64 + sseg * 8], &As[bufi][idx * 8]);
      gl_lds16(&B[(long)(n0 + row) * K + kt * 64 + sseg * 8], &Bs[bufi][idx * 8]);
    }
  };

  stage(0, 0);
  for (int kt = 0; kt < NT; ++kt) {
    const int bufi = kt & 1;
    if (kt + 1 < NT) {
      stage(kt + 1, bufi ^ 1);
      asm volatile("s_waitcnt vmcnt(8)" ::: "memory");
    } else {
      asm volatile("s_waitcnt vmcnt(0)" ::: "memory");
    }
    asm volatile("s_barrier" ::: "memory");
#pragma unroll
    for (int ks = 0; ks < 64; ks += 32) {
      const int sw = ks ? sw1 : sw0;
      bf16x8 af[4], bfg[4];
#pragma unroll
      for (int i = 0; i < 4; ++i)
        af[i] = *(const bf16x8*)&As[bufi][(wr * 64 + i * 16 + l15) * 64 + sw];
#pragma unroll
      for (int j = 0; j < 4; ++j)
        bfg[j] = *(const bf16x8*)&Bs[bufi][(wc * 64 + j * 16 + l15) * 64 + sw];
#pragma unroll
      for (int i = 0; i < 4; ++i)
#pragma unroll
        for (int j = 0; j < 4; ++j)
          acc[i][j] = __builtin_amdgcn_mfma_f32_16x16x32_bf16(af[i], bfg[j], acc[i][j], 0, 0, 0);
    }
    asm volatile("s_barrier" ::: "memory");
  }

  float cb[4];
  if (!rowbias) {
#pragma unroll
    for (int j = 0; j < 4; ++j) cb[j] = bias[n0 + wc * 64 + j * 16 + l15];
  }

#pragma unroll
  for (int i = 0; i < 4; ++i) {
#pragma unroll
    for (int r = 0; r < 4; ++r) {
      int row = m0 + wr * 64 + i * 16 + quad * 4 + r;
      long base = (long)row * ldc + n0 + wc * 64;
      float rb_ = rowbias ? bias[row] : 0.f;
#pragma unroll
      for (int j = 0; j < 4; ++j) {
        float v = acc[i][j][r] + (rowbias ? rb_ : cb[j]);
        if (STORE_BF16) ((u16*)Cout)[base + j * 16 + l15] = f2bf(v);
        else            ((float*)Cout)[base + j * 16 + l15] = v;
      }
    }
  }
}

// ---------------------------------------------------------------- fused QKV + V^T GEMM
// XCD-aware remap: same-B-tile blocks sit at stride-16 (Q/K) / stride-32 (V^T)
// indices, i.e. identical mod 8 -> one XCD's L2 owns each B-tile (round-robin
// dispatch heuristic; worst case neutral).
__global__ __launch_bounds__(256) void gemm_qkv(
    const u16* __restrict__ xb, const u16* __restrict__ wqb,
    const u16* __restrict__ wkb, const u16* __restrict__ wvb,
    const float* __restrict__ bq, const float* __restrict__ bk,
    const float* __restrict__ bv,
    u16* __restrict__ Qb, u16* __restrict__ Kb, u16* __restrict__ Vtg) {
  const int bx = blockIdx.x;
  const u16 *AT, *BT;
  const float* bias;
  u16* C;
  int m0, n0, ldc;
  bool rowbias;
  if (bx < 512) {
    int g = bx & 15;              // B-group: 0..7 Q, 8..15 K
    int sel = g >> 3;
    n0 = (g & 7) * 128;
    m0 = (bx >> 4) * 128;         // 0..31
    AT = xb; BT = sel ? wkb : wqb; bias = sel ? bk : bq;
    C = sel ? Kb : Qb; ldc = 1024; rowbias = false;
  } else {
    int rem = bx - 512;
    n0 = (rem & 31) * 128;        // xb n-tile (B); same-n at stride-32 -> co-XCD
    m0 = (rem >> 5) * 128;        // Wv m-tile 0..7
    AT = wvb; BT = xb; bias = bv;
    C = Vtg; ldc = 4096; rowbias = true;
  }
  gemm_body<true>(AT, BT, bias, rowbias, C, ldc, m0, n0);
}

// ---------------------------------------------------------------- output GEMM
// 256 linear blocks; m = bx>>3, n = bx&7 -> same-B blocks co-XCD.
__global__ __launch_bounds__(256) void gemm_out(
    const u16* __restrict__ A, const u16* __restrict__ B,
    const float* __restrict__ bias, float* __restrict__ C) {
  const int bx = blockIdx.x;
  gemm_body<false>(A, B, bias, false, C, 1024, (bx >> 3) * 128, (bx & 7) * 128);
}

// ---------------------------------------------------------------- attention
// 512 threads = 8 waves; block = (b,h, 128-row q-strip), LPT order. K/V staged via
// source-swizzled global_load_lds (landing layout identical to r10's register path:
// LDS[row][s] = global[row][s^(row&7)]); frag reads at sw0/sw1 recover it (conflicts
// measured 0). __syncthreads provides the vmcnt drain for gl_lds.
__global__ __launch_bounds__(512) void attn_strip(
    const u16* __restrict__ Qb,     // [4096][1024]
    const u16* __restrict__ Kb,     // [4096][1024]
    const u16* __restrict__ Vtg,    // [1024][4096] V^T
    const float* __restrict__ rel_bias,  // [63][16]
    u16* __restrict__ att) {        // == Qb (in-place, disjoint rows)
  constexpr int WS = 68;
  __shared__ __align__(16) u16 Kt[64 * 64];
  __shared__ __align__(16) u16 Vt[64 * 64];
  __shared__ __align__(16) u16 Ws[8][16 * WS];
  __shared__ float biasl[64];

  const int bx = blockIdx.x;
  const int strip = 7 - (bx >> 6);   // LPT: longest chains dispatch first
  const int bh = bx & 63;
  const int b = bh >> 4, h = bh & 15;
  const int q0 = strip * 128;
  const int cend = 2 * strip + 1;

  const int t = threadIdx.x;
  const int lane = t & 63;
  const int wv = t >> 6;          // 0..7
  const int quad = lane >> 4;
  const int l15 = lane & 15;

  if (t < 63) biasl[t] = rel_bias[t * 16 + h];
  const float b0c = rel_bias[h];  // clipped bias for dd <= -31

  const long qrow = (long)(b * 1024 + q0 + wv * 16 + l15) * 1024 + h * 64;
  bf16x8 qf0 = *(const bf16x8*)&Qb[qrow + quad * 8];
  bf16x8 qf1 = *(const bf16x8*)&Qb[qrow + 32 + quad * 8];

  const f32x4 vzero = {0.f, 0.f, 0.f, 0.f};
  f32x4 acc_o[4];
#pragma unroll
  for (int j = 0; j < 4; ++j) acc_o[j] = vzero;
  float denom = 0.f;
  const float scale = 0.125f;  // 64^-0.5
  const int ql = q0 + wv * 16 + l15;
  const int sw0 = (quad ^ (l15 & 7)) * 8;
  const int sw1 = ((4 + quad) ^ (l15 & 7)) * 8;

  const int srow = t >> 3;                 // staging row 0..63
  const int sseg = (t & 7) ^ (srow & 7);   // source-side swizzle

  for (int c = 0; c <= cend; ++c) {
    const int k0 = c * 64;
    if (c) __syncthreads();
    // stage K [key][d] and V^T [d][key] via gl_lds (16B/lane, swizzled source)
    gl_lds16(&Kb[(long)(b * 1024 + k0 + srow) * 1024 + h * 64 + sseg * 8], &Kt[t * 8]);
    gl_lds16(&Vtg[(long)(h * 64 + srow) * 4096 + b * 1024 + k0 + sseg * 8], &Vt[t * 8]);
    __syncthreads();

    const bool fast = (c <= 2 * strip - 2);
#pragma unroll
    for (int g = 0; g < 4; ++g) {
      const u16* kr = &Kt[(g * 16 + l15) * 64];
      bf16x8 kf0 = *(const bf16x8*)&kr[sw0];
      bf16x8 kf1 = *(const bf16x8*)&kr[sw1];
      f32x4 sT = vzero;
      sT = __builtin_amdgcn_mfma_f32_16x16x32_bf16(kf0, qf0, sT, 0, 0, 0);
      sT = __builtin_amdgcn_mfma_f32_16x16x32_bf16(kf1, qf1, sT, 0, 0, 0);
      const int kgb = k0 + g * 16 + quad * 4;
      ushort4 wpk;
      if (fast) {
#pragma unroll
        for (int r = 0; r < 4; ++r) {
          float w = fmaxf(sT[r] * scale + b0c, 0.f) + 1e-6f;
          u16 wb = f2bf(w);
          denom += bf2f(wb);
          ((u16*)&wpk)[r] = wb;
        }
      } else {
#pragma unroll
        for (int r = 0; r < 4; ++r) {
          int kg = kgb + r;
          int dd = kg - ql;
          dd = dd < -31 ? -31 : (dd > 31 ? 31 : dd);
          float sv = sT[r] * scale + biasl[dd + 31];
          float w = (kg <= ql) ? (fmaxf(sv, 0.f) + 1e-6f) : 0.f;
          u16 wb = f2bf(w);
          denom += bf2f(wb);
          ((u16*)&wpk)[r] = wb;
        }
      }
      *(ushort4*)&Ws[wv][l15 * WS + g * 16 + quad * 4] = wpk;
    }
    asm volatile("s_waitcnt lgkmcnt(0)" ::: "memory");   // Ws wave-private W->R
#pragma unroll
    for (int ks = 0; ks < 64; ks += 32) {
      union { bf16x8 v8; bf16x4 v4[2]; } au;
      int wbase = l15 * WS + ks + quad * 8;
      au.v4[0] = *(const bf16x4*)&Ws[wv][wbase];
      au.v4[1] = *(const bf16x4*)&Ws[wv][wbase + 4];
      const int sv = ks ? sw1 : sw0;
#pragma unroll
      for (int j = 0; j < 4; ++j) {
        bf16x8 bvv = *(const bf16x8*)&Vt[(j * 16 + l15) * 64 + sv];
        acc_o[j] = __builtin_amdgcn_mfma_f32_16x16x32_bf16(au.v8, bvv, acc_o[j], 0, 0, 0);
      }
    }
  }

  // denom for q=l15: reduce across the 4 quads
  denom += __shfl_xor(denom, 16);
  denom += __shfl_xor(denom, 32);

  float invm = 1.f / (denom + 1e-6f);
  float inv[4];
#pragma unroll
  for (int r = 0; r < 4; ++r) inv[r] = __shfl(invm, quad * 4 + r);
#pragma unroll
  for (int j = 0; j < 4; ++j)
#pragma unroll
    for (int r = 0; r < 4; ++r) {
      int q = q0 + wv * 16 + quad * 4 + r;
      att[(long)(b * 1024 + q) * 1024 + h * 64 + j * 16 + l15] = f2bf(acc_o[j][r] * inv[r]);
    }
}

// ---------------------------------------------------------------- launch
extern "C" void kernel_launch(void* const* d_in, const int* in_sizes, int n_in,
                              void* d_out, int out_size, void* d_ws, size_t ws_size,
                              hipStream_t stream) {
  const float* x  = (const float*)d_in[0];
  const float* Wq = (const float*)d_in[2];
  const float* bq = (const float*)d_in[3];
  const float* Wk = (const float*)d_in[4];
  const float* bk = (const float*)d_in[5];
  const float* Wv = (const float*)d_in[6];
  const float* bv = (const float*)d_in[7];
  const float* Wo = (const float*)d_in[8];
  const float* bo = (const float*)d_in[9];
  const float* rb = (const float*)d_in[10];

  char* ws = (char*)d_ws;
  u16* xb  = (u16*)(ws);
  u16* wqb = (u16*)(ws + (8l  << 20));
  u16* wkb = (u16*)(ws + (10l << 20));
  u16* wvb = (u16*)(ws + (12l << 20));
  u16* wob = (u16*)(ws + (14l << 20));
  u16* Qb  = (u16*)(ws + (16l << 20));
  u16* Kb  = (u16*)d_out;
  u16* Vtg = (u16*)((char*)d_out + (8l << 20));

  cast_all_kernel<<<8192, 256, 0, stream>>>(x, Wq, Wk, Wv, Wo, xb, wqb, wkb, wvb, wob);
  gemm_qkv<<<768, 256, 0, stream>>>(xb, wqb, wkb, wvb, bq, bk, bv, Qb, Kb, Vtg);
  attn_strip<<<512, 512, 0, stream>>>(Qb, Kb, Vtg, rb, Qb);
  gemm_out<<<256, 256, 0, stream>>>(Qb, wob, bo, (float*)d_out);
}